// Round 9
// baseline (247.846 us; speedup 1.0000x reference)
//
#include <hip/hip_runtime.h>

typedef __attribute__((ext_vector_type(8))) __bf16 bf16x8;
typedef __attribute__((ext_vector_type(8))) _Float16 f16x8;
typedef __attribute__((ext_vector_type(4))) float f32x4;
typedef __attribute__((ext_vector_type(16))) float f32x16;
typedef __attribute__((ext_vector_type(8))) unsigned short u16x8;

#define MFMA_BF16(a, b, c) __builtin_amdgcn_mfma_f32_16x16x32_bf16((a), (b), (c), 0, 0, 0)
#define MFMA32_BF16(a, b, c) __builtin_amdgcn_mfma_f32_32x32x16_bf16((a), (b), (c), 0, 0, 0)
#define MFMA32_F16(a, b, c)  __builtin_amdgcn_mfma_f32_32x32x16_f16((a), (b), (c), 0, 0, 0)
#define LOG2E 1.44269504088896340736f
#define QSCALE 0.18033688011112042f   // 0.125 * log2(e), folded into wq at cvt

__device__ __forceinline__ float b2f(unsigned short u) {
    union { unsigned int i; float f; } v; v.i = ((unsigned int)u) << 16; return v.f;
}
__device__ __forceinline__ unsigned short f2bf(float f) {
    union { float f; unsigned int i; } v; v.f = f;
    unsigned int u = v.i;
    return (unsigned short)((u + 0x7fffu + ((u >> 16) & 1u)) >> 16);
}

// async global->LDS, 16B/lane. HW dest = wave-uniform base + lane*16 (m104).
// Swizzle is applied on the GLOBAL side so conflict-free LDS layouts coexist with it.
__device__ __forceinline__ void gl_lds16(const void* g, void* l) {
    __builtin_amdgcn_global_load_lds(
        (const __attribute__((address_space(1))) void*)g,
        (__attribute__((address_space(3))) void*)l,
        16, 0, 0);
}

// ---------------- fp32 -> bf16 conversion of all 5 inputs; wq pre-scaled ----------
__global__ __launch_bounds__(256) void cvt_all(const float* __restrict__ x,
                                               const float* __restrict__ wq,
                                               const float* __restrict__ wk,
                                               const float* __restrict__ wv,
                                               const float* __restrict__ wo,
                                               unsigned short* __restrict__ xb,
                                               unsigned short* __restrict__ wqb,
                                               unsigned short* __restrict__ wkb,
                                               unsigned short* __restrict__ wvb,
                                               unsigned short* __restrict__ wob) {
    int id = blockIdx.x * 256 + threadIdx.x;  // [0, 1M)
    const float* src; unsigned short* dst; size_t off; float scl = 1.0f;
    if (id < 524288)      { src = x;  dst = xb;  off = (size_t)id * 8; }
    else if (id < 655360) { src = wq; dst = wqb; off = (size_t)(id - 524288) * 8; scl = QSCALE; }
    else if (id < 786432) { src = wk; dst = wkb; off = (size_t)(id - 655360) * 8; }
    else if (id < 917504) { src = wv; dst = wvb; off = (size_t)(id - 786432) * 8; }
    else                  { src = wo; dst = wob; off = (size_t)(id - 917504) * 8; }
    float4 a = *(const float4*)(src + off);
    float4 b = *(const float4*)(src + off + 4);
    u16x8 o;
    o[0] = f2bf(a.x * scl); o[1] = f2bf(a.y * scl); o[2] = f2bf(a.z * scl); o[3] = f2bf(a.w * scl);
    o[4] = f2bf(b.x * scl); o[5] = f2bf(b.y * scl); o[6] = f2bf(b.z * scl); o[7] = f2bf(b.w * scl);
    *(u16x8*)(dst + off) = o;
}

// ---------------- GEMM core: C[MxN] = A[MxK]*B[NxK]^T, bf16 in, fp32 accum --------
// 128x128 tile, BK=32, K=1024 fixed, A/B row stride 1024. LDS chunk (r,cpos) holds
// source chunk cpos^((r>>1)&3) -> frag ds_read_b128 is 2-way (free).
// MODE: 0 = bf16 out, 1 = f32 out, 2 = f16 out, 3 = bf16 out with fused RoPE.
template <int MODE>
__device__ __forceinline__ void gemm128_bt(const unsigned short* __restrict__ A,
                                           const unsigned short* __restrict__ B,
                                           void* __restrict__ Cv,
                                           int m0, int n0, int ldc,
                                           unsigned short* As, unsigned short* Bs) {
    const int tid = threadIdx.x;
    const int w = tid >> 6, lane = tid & 63;
    const int quad = lane >> 4, l15 = lane & 15;
    const int wm = w & 1, wn = w >> 1;

    f32x4 acc[4][4];
#pragma unroll
    for (int mt = 0; mt < 4; ++mt)
#pragma unroll
        for (int nt = 0; nt < 4; ++nt) acc[mt][nt] = f32x4{0.f, 0.f, 0.f, 0.f};

    for (int k0 = 0; k0 < 1024; k0 += 32) {
        __syncthreads();
#pragma unroll
        for (int i = 0; i < 2; ++i) {
            int L = (w * 2 + i) * 64 + lane;      // chunk index in tile
            int r = L >> 2;
            int c = (L & 3) ^ ((r >> 1) & 3);     // swizzled source chunk
            gl_lds16(A + (size_t)(m0 + r) * 1024 + k0 + c * 8, As + L * 8);
            gl_lds16(B + (size_t)(n0 + r) * 1024 + k0 + c * 8, Bs + L * 8);
        }
        __syncthreads();

        bf16x8 af[4], bfr[4];
#pragma unroll
        for (int mt = 0; mt < 4; ++mt) {
            int row = wm * 64 + mt * 16 + l15;
            af[mt] = *(const bf16x8*)(As + row * 32 + (quad ^ ((row >> 1) & 3)) * 8);
        }
#pragma unroll
        for (int nt = 0; nt < 4; ++nt) {
            int row = wn * 64 + nt * 16 + l15;
            bfr[nt] = *(const bf16x8*)(Bs + row * 32 + (quad ^ ((row >> 1) & 3)) * 8);
        }
#pragma unroll
        for (int mt = 0; mt < 4; ++mt)
#pragma unroll
            for (int nt = 0; nt < 4; ++nt)
                acc[mt][nt] = MFMA_BF16(af[mt], bfr[nt], acc[mt][nt]);
    }

    // ---- fused RoPE (MODE 3): ch = nt*16+l15 (row-independent), pp = ch>>1 ----
    float invf[4], sgn = 0.f;
    if constexpr (MODE == 3) {
        sgn = (l15 & 1) ? 1.0f : -1.0f;   // odd lane: +p*sin ; even lane: -p*sin
#pragma unroll
        for (int nt = 0; nt < 4; ++nt)
            invf[nt] = exp2f(-0.41524101186092029f * (float)((nt * 16 + l15) >> 1));
    }

#pragma unroll
    for (int mt = 0; mt < 4; ++mt) {
        int grow = m0 + wm * 64 + mt * 16 + quad * 4;
#pragma unroll
        for (int nt = 0; nt < 4; ++nt) {
            int gcol = n0 + wn * 64 + nt * 16 + l15;
#pragma unroll
            for (int r = 0; r < 4; ++r) {
                float val = acc[mt][nt][r];
                size_t idx = (size_t)(grow + r) * ldc + gcol;
                if constexpr (MODE == 0) {
                    ((unsigned short*)Cv)[idx] = f2bf(val);
                } else if constexpr (MODE == 1) {
                    ((float*)Cv)[idx] = val;
                } else if constexpr (MODE == 2) {
                    _Float16 hv = (_Float16)val;
                    ((unsigned short*)Cv)[idx] = __builtin_bit_cast(unsigned short, hv);
                } else {
                    float p = __shfl_xor(val, 1);              // pair partner channel
                    float pos = (float)((grow + r) & 2047);    // seq position
                    float ang = pos * invf[nt];
                    float out = val * __cosf(ang) + sgn * p * __sinf(ang);
                    ((unsigned short*)Cv)[idx] = f2bf(out);
                }
            }
        }
    }
}

// Q/K: bf16 + fused RoPE (ldc 1024). V: C = Wv * X^T = V^T[ch][token] f16 (ldc 4096).
__global__ __launch_bounds__(256) void gemm_qkv(const unsigned short* __restrict__ X,
                                                const unsigned short* __restrict__ Wq,
                                                const unsigned short* __restrict__ Wk,
                                                const unsigned short* __restrict__ Wv,
                                                unsigned short* __restrict__ Qo,
                                                unsigned short* __restrict__ Ko,
                                                unsigned short* __restrict__ Vt) {
    __shared__ unsigned short As[128 * 32];
    __shared__ unsigned short Bs[128 * 32];
    int y = blockIdx.y;
    if (y < 16) {
        int sel = y >> 3;
        int m0 = blockIdx.x * 128;         // tokens
        int n0 = (y & 7) * 128;            // channels
        const unsigned short* B = sel ? Wk : Wq;
        unsigned short* C = sel ? Ko : Qo;
        gemm128_bt<3>(X, B, C, m0, n0, 1024, As, Bs);
    } else {
        int m0 = (y & 7) * 128;            // channels
        int n0 = blockIdx.x * 128;         // tokens
        gemm128_bt<2>(Wv, X, Vt, m0, n0, 4096, As, Bs);
    }
}

__global__ __launch_bounds__(256) void gemm_out(const unsigned short* __restrict__ A,
                                                const unsigned short* __restrict__ Wo,
                                                float* __restrict__ C) {
    __shared__ unsigned short As[128 * 32];
    __shared__ unsigned short Bs[128 * 32];
    gemm128_bt<1>(A, Wo, C, blockIdx.x * 128, blockIdx.y * 128, 1024, As, Bs);
}

// ---------------- Flash attention, 32x32x16 MFMA, causal, M=0 ----------------------
// Block = 2 waves x 32 q-rows; grid 1024 (32 qt x 32 bh, XCD map as before).
// 32x32 fragments double FLOP per LDS read vs 16x16 (the round-8 LDS-pipe floor).
// A-layouts: X[m=lane&31][k=(lane>>5)*8+j]; C/D: col=lane&31,
// row=(reg&3)+8*(reg>>2)+4*(lane>>5). Rowsum via ones-MFMA; mask on diagonal only.
#define FBODY32(KB, MASKED)                                                             \
    {                                                                                   \
        const int kb_ = (KB);                                                           \
        f32x16 s0 = {0.f}, s1 = {0.f};                                                  \
        _Pragma("unroll")                                                               \
        for (int kc = 0; kc < 4; ++kc) {                                                \
            int ch = kc * 2 + hi;                                                       \
            bf16x8 kf0 = *(const bf16x8*)(Ks + k31 * 64 + ((ch ^ (k31 & 7)) * 8));      \
            bf16x8 kf1 = *(const bf16x8*)(Ks + (32 + k31) * 64 + ((ch ^ (k31 & 7)) * 8));\
            s0 = MFMA32_BF16(qf[kc], kf0, s0);                                          \
            s1 = MFMA32_BF16(qf[kc], kf1, s1);                                          \
        }                                                                               \
        _Pragma("unroll")                                                               \
        for (int r = 0; r < 16; ++r) {                                                  \
            int qrow = (r & 3) + 8 * (r >> 2) + 4 * hi;                                 \
            float e0 = exp2f(s0[r]);                                                    \
            float e1 = exp2f(s1[r]);                                                    \
            if (MASKED) {                                                               \
                int qpos = qpos0 + qrow;                                                \
                e0 = (kb_ * 64 + k31 > qpos) ? 0.f : e0;                                \
                e1 = (kb_ * 64 + 32 + k31 > qpos) ? 0.f : e1;                           \
            }                                                                           \
            _Float16 h0 = (_Float16)e0, h1 = (_Float16)e1;                              \
            Pw[qrow * 72 + k31]      = __builtin_bit_cast(unsigned short, h0);          \
            Pw[qrow * 72 + 32 + k31] = __builtin_bit_cast(unsigned short, h1);          \
        }                                                                               \
        __asm__ volatile("s_waitcnt lgkmcnt(0)" ::: "memory");                          \
        f16x8 pf[4];                                                                    \
        _Pragma("unroll")                                                               \
        for (int kc = 0; kc < 4; ++kc)                                                  \
            pf[kc] = *(const f16x8*)(Pw + k31 * 72 + kc * 16 + hi * 8);                 \
        _Pragma("unroll")                                                               \
        for (int kc = 0; kc < 4; ++kc) lacc = MFMA32_F16(pf[kc], ones, lacc);           \
        _Pragma("unroll")                                                               \
        for (int kc = 0; kc < 4; ++kc) {                                                \
            int ch = kc * 2 + hi;                                                       \
            f16x8 vf0 = *(const f16x8*)(Vs + k31 * 64 + ((ch ^ (k31 & 7)) * 8));        \
            f16x8 vf1 = *(const f16x8*)(Vs + (32 + k31) * 64 + ((ch ^ (k31 & 7)) * 8)); \
            accO0 = MFMA32_F16(pf[kc], vf0, accO0);                                     \
            accO1 = MFMA32_F16(pf[kc], vf1, accO1);                                     \
        }                                                                               \
    }

__global__ __launch_bounds__(128, 3) void flash_attn(const unsigned short* __restrict__ Q,
                                                     const unsigned short* __restrict__ Kb,
                                                     const unsigned short* __restrict__ Vt,
                                                     unsigned short* __restrict__ O) {
    int id = blockIdx.x;
    int xcd = id & 7;
    int sl = id >> 3;           // slot within XCD, [0,128)
    int rr = sl >> 5;           // 0..3
    int j  = sl & 31;
    int qt;
    if (rr == 0)      qt = j;
    else if (rr == 1) qt = 31 - j;
    else if (rr == 2) qt = (j + 16) & 31;
    else              qt = 31 - ((j + 16) & 31);
    int bh = xcd + 8 * rr;      // 4 bh per XCD -> K/V stream L2-resident
    int b = bh >> 4, h = bh & 15;
    int tid = threadIdx.x, w = tid >> 6, lane = tid & 63;
    const int k31 = lane & 31, hi = lane >> 5;
    int qbase = b * 2048 + qt * 64 + w * 32;    // global token row base (wave)
    int qpos0 = qt * 64 + w * 32;               // sequence position base (wave)

    __shared__ unsigned short Ks[64 * 64];      // bf16 [key][d], chunk-swizzled
    __shared__ unsigned short Vs[64 * 64];      // f16  [d_row? no: [d? ] see below
    // Vs rows: B-frag n=d => row index = d in [0,64), cols = key. Staged from Vt.
    __shared__ unsigned short Ps[2][32 * 72];   // f16 P [q][key], stride 72, per wave

    // Q A-frags: qf[kc] = Q[qbase + k31][h*64 + kc*16 + hi*8 .. +7]
    bf16x8 qf[4];
#pragma unroll
    for (int kc = 0; kc < 4; ++kc)
        qf[kc] = *(const bf16x8*)(Q + (size_t)(qbase + k31) * 1024 + h * 64 + kc * 16 + hi * 8);

    f16x8 ones;
#pragma unroll
    for (int jj = 0; jj < 8; ++jj) ones[jj] = (_Float16)1.0f;

    // staging: 512 chunks per tile, 128 lanes x 4 iters. chunk L: row r=L>>3,
    // lds col cpos=L&7 holds source chunk cpos^(r&7).
    const unsigned short* KgA[4];
    const unsigned short* VgA[4];
    int Ldst[4];
#pragma unroll
    for (int i = 0; i < 4; ++i) {
        int L = i * 128 + tid;
        int r = L >> 3, cpos = L & 7;
        int c = cpos ^ (r & 7);
        Ldst[i] = L * 8;
        KgA[i] = Kb + (size_t)(b * 2048 + r) * 1024 + h * 64 + c * 8;
        VgA[i] = Vt + (size_t)(h * 64 + r) * 4096 + b * 2048 + c * 8;
    }

    f32x16 accO0 = {0.f}, accO1 = {0.f};
    f32x16 lacc = {0.f};
    unsigned short* Pw = Ps[w];

    for (int kb = 0; kb <= qt; ++kb) {
        __syncthreads();                     // previous compute done before restage
        {
            size_t ko = (size_t)kb * 64 * 1024;
            size_t vo = (size_t)kb * 64;
#pragma unroll
            for (int i = 0; i < 4; ++i) {
                gl_lds16(KgA[i] + ko, Ks + Ldst[i]);
                gl_lds16(VgA[i] + vo, Vs + Ldst[i]);
            }
        }
        __syncthreads();                     // vmcnt drain + visibility
        if (kb < qt) {
            FBODY32(kb, 0)
        } else {
            FBODY32(kb, 1)
        }
    }

    // ---- epilogue: O[q][d] = accO / rowsum (lacc reg r = rowsum of its q-row) ----
    float inv[16];
#pragma unroll
    for (int r = 0; r < 16; ++r) inv[r] = 1.0f / lacc[r];
#pragma unroll
    for (int r = 0; r < 16; ++r) {
        int qrow = (r & 3) + 8 * (r >> 2) + 4 * hi;
        size_t base = (size_t)(qbase + qrow) * 1024 + h * 64;
        O[base + k31]      = f2bf(accO0[r] * inv[r]);
        O[base + 32 + k31] = f2bf(accO1[r] * inv[r]);
    }
}

extern "C" void kernel_launch(void* const* d_in, const int* in_sizes, int n_in,
                              void* d_out, int out_size, void* d_ws, size_t ws_size,
                              hipStream_t stream) {
    (void)in_sizes; (void)n_in; (void)out_size; (void)ws_size;
    const float* x  = (const float*)d_in[0];
    const float* wq = (const float*)d_in[1];
    const float* wk = (const float*)d_in[2];
    const float* wv = (const float*)d_in[3];
    const float* wo = (const float*)d_in[4];
    float* out = (float*)d_out;

    const size_t T = (size_t)4096 * 1024;
    const size_t W = (size_t)1024 * 1024;
    unsigned short* Q   = (unsigned short*)d_ws;
    unsigned short* K   = Q + T;
    unsigned short* Vt  = K + T;      // f16 [ch][token], ldc 4096
    unsigned short* xb  = Vt + T;
    unsigned short* AO  = xb;         // alias: xb dead after gemm_qkv
    unsigned short* wqb = xb + T;
    unsigned short* wkb = wqb + W;
    unsigned short* wvb = wkb + W;
    unsigned short* wob = wvb + W;

    cvt_all  <<<dim3(4096),   256, 0, stream>>>(x, wq, wk, wv, wo, xb, wqb, wkb, wvb, wob);
    gemm_qkv <<<dim3(32, 24), 256, 0, stream>>>(xb, wqb, wkb, wvb, Q, K, Vt);
    flash_attn<<<dim3(1024),  128, 0, stream>>>(Q, K, Vt, AO);
    gemm_out <<<dim3(32, 8),  256, 0, stream>>>(AO, wob, out);
}

// Round 10
// 200.186 us; speedup vs baseline: 1.2381x; 1.2381x over previous
//
#include <hip/hip_runtime.h>

typedef __attribute__((ext_vector_type(8))) __bf16 bf16x8;
typedef __attribute__((ext_vector_type(8))) _Float16 f16x8;
typedef __attribute__((ext_vector_type(4))) float f32x4;
typedef __attribute__((ext_vector_type(8))) unsigned short u16x8;

#define MFMA_BF16(a, b, c) __builtin_amdgcn_mfma_f32_16x16x32_bf16((a), (b), (c), 0, 0, 0)
#define MFMA_F16(a, b, c)  __builtin_amdgcn_mfma_f32_16x16x32_f16((a), (b), (c), 0, 0, 0)
#define LOG2E 1.44269504088896340736f
#define QSCALE 0.18033688011112042f   // 0.125 * log2(e), folded into wq at cvt

__device__ __forceinline__ float b2f(unsigned short u) {
    union { unsigned int i; float f; } v; v.i = ((unsigned int)u) << 16; return v.f;
}
__device__ __forceinline__ unsigned short f2bf(float f) {
    union { float f; unsigned int i; } v; v.f = f;
    unsigned int u = v.i;
    return (unsigned short)((u + 0x7fffu + ((u >> 16) & 1u)) >> 16);
}

// async global->LDS, 16B/lane. HW dest = wave-uniform base + lane*16 (m104).
// Swizzle is applied on the GLOBAL side so conflict-free LDS layouts coexist with it.
__device__ __forceinline__ void gl_lds16(const void* g, void* l) {
    __builtin_amdgcn_global_load_lds(
        (const __attribute__((address_space(1))) void*)g,
        (__attribute__((address_space(3))) void*)l,
        16, 0, 0);
}

// ---------------- fp32 -> bf16 conversion of all 5 inputs; wq pre-scaled ----------
__global__ __launch_bounds__(256) void cvt_all(const float* __restrict__ x,
                                               const float* __restrict__ wq,
                                               const float* __restrict__ wk,
                                               const float* __restrict__ wv,
                                               const float* __restrict__ wo,
                                               unsigned short* __restrict__ xb,
                                               unsigned short* __restrict__ wqb,
                                               unsigned short* __restrict__ wkb,
                                               unsigned short* __restrict__ wvb,
                                               unsigned short* __restrict__ wob) {
    int id = blockIdx.x * 256 + threadIdx.x;  // [0, 1M)
    const float* src; unsigned short* dst; size_t off; float scl = 1.0f;
    if (id < 524288)      { src = x;  dst = xb;  off = (size_t)id * 8; }
    else if (id < 655360) { src = wq; dst = wqb; off = (size_t)(id - 524288) * 8; scl = QSCALE; }
    else if (id < 786432) { src = wk; dst = wkb; off = (size_t)(id - 655360) * 8; }
    else if (id < 917504) { src = wv; dst = wvb; off = (size_t)(id - 786432) * 8; }
    else                  { src = wo; dst = wob; off = (size_t)(id - 917504) * 8; }
    float4 a = *(const float4*)(src + off);
    float4 b = *(const float4*)(src + off + 4);
    u16x8 o;
    o[0] = f2bf(a.x * scl); o[1] = f2bf(a.y * scl); o[2] = f2bf(a.z * scl); o[3] = f2bf(a.w * scl);
    o[4] = f2bf(b.x * scl); o[5] = f2bf(b.y * scl); o[6] = f2bf(b.z * scl); o[7] = f2bf(b.w * scl);
    *(u16x8*)(dst + off) = o;
}

// ---------------- GEMM core: C[MxN] = A[MxK]*B[NxK]^T, bf16 in, fp32 accum --------
// 128x128 tile, BK=32, K=1024 fixed, A/B row stride 1024. LDS chunk (r,cpos) holds
// source chunk cpos^((r>>1)&3) -> frag ds_read_b128 is 2-way (free).
// MODE: 0 = bf16 out, 1 = f32 out, 2 = f16 out, 3 = bf16 out with fused RoPE.
template <int MODE>
__device__ __forceinline__ void gemm128_bt(const unsigned short* __restrict__ A,
                                           const unsigned short* __restrict__ B,
                                           void* __restrict__ Cv,
                                           int m0, int n0, int ldc,
                                           unsigned short* As, unsigned short* Bs) {
    const int tid = threadIdx.x;
    const int w = tid >> 6, lane = tid & 63;
    const int quad = lane >> 4, l15 = lane & 15;
    const int wm = w & 1, wn = w >> 1;

    f32x4 acc[4][4];
#pragma unroll
    for (int mt = 0; mt < 4; ++mt)
#pragma unroll
        for (int nt = 0; nt < 4; ++nt) acc[mt][nt] = f32x4{0.f, 0.f, 0.f, 0.f};

    for (int k0 = 0; k0 < 1024; k0 += 32) {
        __syncthreads();
#pragma unroll
        for (int i = 0; i < 2; ++i) {
            int L = (w * 2 + i) * 64 + lane;      // chunk index in tile
            int r = L >> 2;
            int c = (L & 3) ^ ((r >> 1) & 3);     // swizzled source chunk
            gl_lds16(A + (size_t)(m0 + r) * 1024 + k0 + c * 8, As + L * 8);
            gl_lds16(B + (size_t)(n0 + r) * 1024 + k0 + c * 8, Bs + L * 8);
        }
        __syncthreads();

        bf16x8 af[4], bfr[4];
#pragma unroll
        for (int mt = 0; mt < 4; ++mt) {
            int row = wm * 64 + mt * 16 + l15;
            af[mt] = *(const bf16x8*)(As + row * 32 + (quad ^ ((row >> 1) & 3)) * 8);
        }
#pragma unroll
        for (int nt = 0; nt < 4; ++nt) {
            int row = wn * 64 + nt * 16 + l15;
            bfr[nt] = *(const bf16x8*)(Bs + row * 32 + (quad ^ ((row >> 1) & 3)) * 8);
        }
#pragma unroll
        for (int mt = 0; mt < 4; ++mt)
#pragma unroll
            for (int nt = 0; nt < 4; ++nt)
                acc[mt][nt] = MFMA_BF16(af[mt], bfr[nt], acc[mt][nt]);
    }

    // ---- fused RoPE (MODE 3): ch = nt*16+l15 (row-independent), pp = ch>>1 ----
    float invf[4], sgn = 0.f;
    if constexpr (MODE == 3) {
        sgn = (l15 & 1) ? 1.0f : -1.0f;   // odd lane: +p*sin ; even lane: -p*sin
#pragma unroll
        for (int nt = 0; nt < 4; ++nt)
            invf[nt] = exp2f(-0.41524101186092029f * (float)((nt * 16 + l15) >> 1));
    }

#pragma unroll
    for (int mt = 0; mt < 4; ++mt) {
        int grow = m0 + wm * 64 + mt * 16 + quad * 4;
#pragma unroll
        for (int nt = 0; nt < 4; ++nt) {
            int gcol = n0 + wn * 64 + nt * 16 + l15;
#pragma unroll
            for (int r = 0; r < 4; ++r) {
                float val = acc[mt][nt][r];
                size_t idx = (size_t)(grow + r) * ldc + gcol;
                if constexpr (MODE == 0) {
                    ((unsigned short*)Cv)[idx] = f2bf(val);
                } else if constexpr (MODE == 1) {
                    ((float*)Cv)[idx] = val;
                } else if constexpr (MODE == 2) {
                    _Float16 hv = (_Float16)val;
                    ((unsigned short*)Cv)[idx] = __builtin_bit_cast(unsigned short, hv);
                } else {
                    float p = __shfl_xor(val, 1);              // pair partner channel
                    float pos = (float)((grow + r) & 2047);    // seq position
                    float ang = pos * invf[nt];
                    float out = val * __cosf(ang) + sgn * p * __sinf(ang);
                    ((unsigned short*)Cv)[idx] = f2bf(out);
                }
            }
        }
    }
}

// Q/K: bf16 + fused RoPE (ldc 1024). V: C = Wv * X^T = V^T[ch][token] f16 (ldc 4096).
__global__ __launch_bounds__(256) void gemm_qkv(const unsigned short* __restrict__ X,
                                                const unsigned short* __restrict__ Wq,
                                                const unsigned short* __restrict__ Wk,
                                                const unsigned short* __restrict__ Wv,
                                                unsigned short* __restrict__ Qo,
                                                unsigned short* __restrict__ Ko,
                                                unsigned short* __restrict__ Vt) {
    __shared__ unsigned short As[128 * 32];
    __shared__ unsigned short Bs[128 * 32];
    int y = blockIdx.y;
    if (y < 16) {
        int sel = y >> 3;
        int m0 = blockIdx.x * 128;         // tokens
        int n0 = (y & 7) * 128;            // channels
        const unsigned short* B = sel ? Wk : Wq;
        unsigned short* C = sel ? Ko : Qo;
        gemm128_bt<3>(X, B, C, m0, n0, 1024, As, Bs);
    } else {
        int m0 = (y & 7) * 128;            // channels
        int n0 = blockIdx.x * 128;         // tokens
        gemm128_bt<2>(Wv, X, Vt, m0, n0, 4096, As, Bs);
    }
}

__global__ __launch_bounds__(256) void gemm_out(const unsigned short* __restrict__ A,
                                                const unsigned short* __restrict__ Wo,
                                                float* __restrict__ C) {
    __shared__ unsigned short As[128 * 32];
    __shared__ unsigned short Bs[128 * 32];
    gemm128_bt<1>(A, Wo, C, blockIdx.x * 128, blockIdx.y * 128, 1024, As, Bs);
}

// ---------------- Flash attention: 16x16 MFMA, 2 q-tiles per wave -----------------
// Block = 4 waves x 32 q-rows = 128 q-rows; grid 512 (16 qt x 32 bh, XCD map).
// K/V fragments are loaded ONCE per iter and feed both q-tiles -> LDS reads per q
// nearly halve vs round 8 (the measured LDS-pipe floor). f32x4 accumulators only
// (round 9's f32x16 spilled to scratch: WRITE_SIZE 8->110MB).
// TM: 0 = unmasked, 1 = diagonal-masked, 2 = skip tile.
#define FB(KB, M0, M1)                                                                  \
    {                                                                                   \
        const int kb_ = (KB);                                                           \
        f32x4 s0[4], s1[4];                                                             \
        _Pragma("unroll")                                                               \
        for (int nt = 0; nt < 4; ++nt) {                                                \
            int row = nt * 16 + l15;                                                    \
            int cof = (quad ^ (row & 7)) * 8;                                           \
            bf16x8 kf0 = *(const bf16x8*)(Ks + row * 64 + cof);                         \
            bf16x8 kf1 = *(const bf16x8*)(Ks + row * 64 + (cof ^ 32));                  \
            f32x4 z = f32x4{0.f, 0.f, 0.f, 0.f};                                        \
            if (M0 != 2) {                                                              \
                s0[nt] = MFMA_BF16(qf[0][0], kf0, z);                                   \
                s0[nt] = MFMA_BF16(qf[0][1], kf1, s0[nt]);                              \
            }                                                                           \
            s1[nt] = MFMA_BF16(qf[1][0], kf0, z);                                       \
            s1[nt] = MFMA_BF16(qf[1][1], kf1, s1[nt]);                                  \
        }                                                                               \
        _Pragma("unroll")                                                               \
        for (int t = 0; t < 2; ++t) {                                                   \
            if (t == 0 && M0 == 2) continue;                                            \
            f32x4* sp = t ? s1 : s0;                                                    \
            const int msk = t ? M1 : M0;                                                \
            unsigned short* Pw = Ps[w][t];                                              \
            _Pragma("unroll")                                                           \
            for (int nt = 0; nt < 4; ++nt) {                                            \
                float e[4];                                                             \
                _Pragma("unroll")                                                       \
                for (int r = 0; r < 4; ++r) {                                           \
                    float ev = exp2f(sp[nt][r]);                                        \
                    if (msk == 1) {                                                     \
                        int kpos = kb_ * 64 + nt * 16 + l15;                            \
                        int qpos = qpos0 + t * 64 + quad * 4 + r;                       \
                        ev = (kpos > qpos) ? 0.f : ev;                                  \
                    }                                                                   \
                    e[r] = ev;                                                          \
                }                                                                       \
                unsigned pk01 = __builtin_bit_cast(unsigned,                            \
                                    __builtin_amdgcn_cvt_pkrtz(e[0], e[1]));            \
                unsigned pk23 = __builtin_bit_cast(unsigned,                            \
                                    __builtin_amdgcn_cvt_pkrtz(e[2], e[3]));            \
                int col = nt * 16 + l15;                                                \
                Pw[(quad * 4 + 0) * 72 + col] = (unsigned short)pk01;                   \
                Pw[(quad * 4 + 1) * 72 + col] = (unsigned short)(pk01 >> 16);           \
                Pw[(quad * 4 + 2) * 72 + col] = (unsigned short)pk23;                   \
                Pw[(quad * 4 + 3) * 72 + col] = (unsigned short)(pk23 >> 16);           \
            }                                                                           \
        }                                                                               \
        __asm__ volatile("s_waitcnt lgkmcnt(0)" ::: "memory");                          \
        f16x8 pf0a, pf1a, pf0b, pf1b;                                                   \
        if (M0 != 2) {                                                                  \
            pf0a = *(const f16x8*)(Ps[w][0] + l15 * 72 + quad * 8);                     \
            pf1a = *(const f16x8*)(Ps[w][0] + l15 * 72 + 32 + quad * 8);                \
            lacc[0] = MFMA_F16(pf0a, ones, lacc[0]);                                    \
            lacc[0] = MFMA_F16(pf1a, ones, lacc[0]);                                    \
        }                                                                               \
        pf0b = *(const f16x8*)(Ps[w][1] + l15 * 72 + quad * 8);                         \
        pf1b = *(const f16x8*)(Ps[w][1] + l15 * 72 + 32 + quad * 8);                    \
        lacc[1] = MFMA_F16(pf0b, ones, lacc[1]);                                        \
        lacc[1] = MFMA_F16(pf1b, ones, lacc[1]);                                        \
        _Pragma("unroll")                                                               \
        for (int nt = 0; nt < 4; ++nt) {                                                \
            int row = nt * 16 + l15;                                                    \
            int cof = (quad ^ (row & 7)) * 8;                                           \
            f16x8 vf0 = *(const f16x8*)(Vs + row * 64 + cof);                           \
            f16x8 vf1 = *(const f16x8*)(Vs + row * 64 + (cof ^ 32));                    \
            if (M0 != 2) {                                                              \
                accO[0][nt] = MFMA_F16(pf0a, vf0, accO[0][nt]);                         \
                accO[0][nt] = MFMA_F16(pf1a, vf1, accO[0][nt]);                         \
            }                                                                           \
            accO[1][nt] = MFMA_F16(pf0b, vf0, accO[1][nt]);                             \
            accO[1][nt] = MFMA_F16(pf1b, vf1, accO[1][nt]);                             \
        }                                                                               \
    }

#define STAGE(KB)                                                                       \
    {                                                                                   \
        size_t ko = (size_t)(KB) * 64 * 1024;                                           \
        size_t vo = (size_t)(KB) * 64;                                                  \
        gl_lds16(Kg0 + ko, Ks + L0 * 8);                                                \
        gl_lds16(Kg1 + ko, Ks + L1 * 8);                                                \
        gl_lds16(Vg0 + vo, Vs + L0 * 8);                                                \
        gl_lds16(Vg1 + vo, Vs + L1 * 8);                                                \
    }

__global__ __launch_bounds__(256, 4) void flash_attn(const unsigned short* __restrict__ Q,
                                                     const unsigned short* __restrict__ Kb,
                                                     const unsigned short* __restrict__ Vt,
                                                     unsigned short* __restrict__ O) {
    int id = blockIdx.x;               // grid 512
    int xcd = id & 7;
    int sl = id >> 3;                  // [0,64)
    int rr = sl >> 4;                  // 0..3
    int j  = sl & 15;
    int qt = (rr & 1) ? (15 - j) : j;  // balanced pairing across rounds
    int bh = xcd + 8 * rr;             // 4 bh per XCD -> K/V streams L2-resident
    int b = bh >> 4, h = bh & 15;
    int tid = threadIdx.x, w = tid >> 6, lane = tid & 63;
    int quad = lane >> 4, l15 = lane & 15;
    int qbase = b * 2048 + qt * 128 + w * 16;   // tile0 row base; tile1 = +64
    int qpos0 = qt * 128 + w * 16;

    __shared__ unsigned short Ks[64 * 64];       // bf16 [key][d], chunk-swizzled
    __shared__ unsigned short Vs[64 * 64];       // f16  [d][key], chunk-swizzled
    __shared__ unsigned short Ps[4][2][16 * 72]; // f16 P scratch per wave per tile

    bf16x8 qf[2][2];
#pragma unroll
    for (int t = 0; t < 2; ++t) {
        const unsigned short* qp =
            Q + (size_t)(qbase + t * 64 + l15) * 1024 + h * 64 + quad * 8;
        qf[t][0] = *(const bf16x8*)qp;
        qf[t][1] = *(const bf16x8*)(qp + 32);
    }
    f16x8 ones;
#pragma unroll
    for (int jj = 0; jj < 8; ++jj) ones[jj] = (_Float16)1.0f;

    // staging: chunk L=(w*2+i)*64+lane; row r=L>>3, lds col cpos=L&7 holds src cpos^(r&7)
    int L0 = w * 128 + lane;
    int L1 = L0 + 64;
    int r0 = L0 >> 3, c0s = (L0 & 7) ^ (r0 & 7);
    int r1 = L1 >> 3, c1s = (L1 & 7) ^ (r1 & 7);
    const unsigned short* Kg0 = Kb + (size_t)(b * 2048 + r0) * 1024 + h * 64 + c0s * 8;
    const unsigned short* Kg1 = Kb + (size_t)(b * 2048 + r1) * 1024 + h * 64 + c1s * 8;
    const unsigned short* Vg0 = Vt + (size_t)(h * 64 + r0) * 4096 + b * 2048 + c0s * 8;
    const unsigned short* Vg1 = Vt + (size_t)(h * 64 + r1) * 4096 + b * 2048 + c1s * 8;

    f32x4 accO[2][4];
#pragma unroll
    for (int t = 0; t < 2; ++t)
#pragma unroll
        for (int nt = 0; nt < 4; ++nt) accO[t][nt] = f32x4{0.f, 0.f, 0.f, 0.f};
    f32x4 lacc[2] = {f32x4{0.f, 0.f, 0.f, 0.f}, f32x4{0.f, 0.f, 0.f, 0.f}};

    int nkb2 = 2 * qt;                 // key-blocks where both tiles are unmasked
    for (int kb = 0; kb < nkb2; ++kb) {
        __syncthreads();
        STAGE(kb)
        __syncthreads();
        FB(kb, 0, 0)
    }
    __syncthreads();
    STAGE(nkb2)
    __syncthreads();
    FB(nkb2, 1, 0)                     // tile0 diagonal, tile1 still clean
    __syncthreads();
    STAGE(nkb2 + 1)
    __syncthreads();
    FB(nkb2 + 1, 2, 1)                 // tile0 done, tile1 diagonal

    // ---- epilogue: O / rowsum (lacc[t] reg r = rowsum of q-row quad*4+r) ----
#pragma unroll
    for (int t = 0; t < 2; ++t) {
        float inv[4];
#pragma unroll
        for (int r = 0; r < 4; ++r) inv[r] = 1.0f / lacc[t][r];
#pragma unroll
        for (int nt = 0; nt < 4; ++nt)
#pragma unroll
            for (int r = 0; r < 4; ++r)
                O[(size_t)(qbase + t * 64 + quad * 4 + r) * 1024 + h * 64 + nt * 16 + l15] =
                    f2bf(accO[t][nt][r] * inv[r]);
    }
}

extern "C" void kernel_launch(void* const* d_in, const int* in_sizes, int n_in,
                              void* d_out, int out_size, void* d_ws, size_t ws_size,
                              hipStream_t stream) {
    (void)in_sizes; (void)n_in; (void)out_size; (void)ws_size;
    const float* x  = (const float*)d_in[0];
    const float* wq = (const float*)d_in[1];
    const float* wk = (const float*)d_in[2];
    const float* wv = (const float*)d_in[3];
    const float* wo = (const float*)d_in[4];
    float* out = (float*)d_out;

    const size_t T = (size_t)4096 * 1024;
    const size_t W = (size_t)1024 * 1024;
    unsigned short* Q   = (unsigned short*)d_ws;
    unsigned short* K   = Q + T;
    unsigned short* Vt  = K + T;      // f16 [ch][token], ldc 4096
    unsigned short* xb  = Vt + T;
    unsigned short* AO  = xb;         // alias: xb dead after gemm_qkv
    unsigned short* wqb = xb + T;
    unsigned short* wkb = wqb + W;
    unsigned short* wvb = wkb + W;
    unsigned short* wob = wvb + W;

    cvt_all  <<<dim3(4096),   256, 0, stream>>>(x, wq, wk, wv, wo, xb, wqb, wkb, wvb, wob);
    gemm_qkv <<<dim3(32, 24), 256, 0, stream>>>(xb, wqb, wkb, wvb, Q, K, Vt);
    flash_attn<<<dim3(512),   256, 0, stream>>>(Q, K, Vt, AO);
    gemm_out <<<dim3(32, 8),  256, 0, stream>>>(AO, wob, out);
}

// Round 11
// 194.003 us; speedup vs baseline: 1.2775x; 1.0319x over previous
//
#include <hip/hip_runtime.h>

typedef __attribute__((ext_vector_type(8))) __bf16 bf16x8;
typedef __attribute__((ext_vector_type(8))) _Float16 f16x8;
typedef __attribute__((ext_vector_type(4))) float f32x4;
typedef __attribute__((ext_vector_type(8))) unsigned short u16x8;

#define MFMA_BF16(a, b, c) __builtin_amdgcn_mfma_f32_16x16x32_bf16((a), (b), (c), 0, 0, 0)
#define MFMA_F16(a, b, c)  __builtin_amdgcn_mfma_f32_16x16x32_f16((a), (b), (c), 0, 0, 0)
#define LOG2E 1.44269504088896340736f
#define QSCALE 0.18033688011112042f   // 0.125 * log2(e), folded into wq at cvt

__device__ __forceinline__ float b2f(unsigned short u) {
    union { unsigned int i; float f; } v; v.i = ((unsigned int)u) << 16; return v.f;
}
__device__ __forceinline__ unsigned short f2bf(float f) {
    union { float f; unsigned int i; } v; v.f = f;
    unsigned int u = v.i;
    return (unsigned short)((u + 0x7fffu + ((u >> 16) & 1u)) >> 16);
}

// async global->LDS, 16B/lane. HW dest = wave-uniform base + lane*16 (m104).
// Swizzle is applied on the GLOBAL side so conflict-free LDS layouts coexist with it.
__device__ __forceinline__ void gl_lds16(const void* g, void* l) {
    __builtin_amdgcn_global_load_lds(
        (const __attribute__((address_space(1))) void*)g,
        (__attribute__((address_space(3))) void*)l,
        16, 0, 0);
}

// ---------------- fp32 -> bf16 conversion of all 5 inputs; wq pre-scaled ----------
__global__ __launch_bounds__(256) void cvt_all(const float* __restrict__ x,
                                               const float* __restrict__ wq,
                                               const float* __restrict__ wk,
                                               const float* __restrict__ wv,
                                               const float* __restrict__ wo,
                                               unsigned short* __restrict__ xb,
                                               unsigned short* __restrict__ wqb,
                                               unsigned short* __restrict__ wkb,
                                               unsigned short* __restrict__ wvb,
                                               unsigned short* __restrict__ wob) {
    int id = blockIdx.x * 256 + threadIdx.x;  // [0, 1M)
    const float* src; unsigned short* dst; size_t off; float scl = 1.0f;
    if (id < 524288)      { src = x;  dst = xb;  off = (size_t)id * 8; }
    else if (id < 655360) { src = wq; dst = wqb; off = (size_t)(id - 524288) * 8; scl = QSCALE; }
    else if (id < 786432) { src = wk; dst = wkb; off = (size_t)(id - 655360) * 8; }
    else if (id < 917504) { src = wv; dst = wvb; off = (size_t)(id - 786432) * 8; }
    else                  { src = wo; dst = wob; off = (size_t)(id - 917504) * 8; }
    float4 a = *(const float4*)(src + off);
    float4 b = *(const float4*)(src + off + 4);
    u16x8 o;
    o[0] = f2bf(a.x * scl); o[1] = f2bf(a.y * scl); o[2] = f2bf(a.z * scl); o[3] = f2bf(a.w * scl);
    o[4] = f2bf(b.x * scl); o[5] = f2bf(b.y * scl); o[6] = f2bf(b.z * scl); o[7] = f2bf(b.w * scl);
    *(u16x8*)(dst + off) = o;
}

// ---------------- GEMM core: C[MxN] = A[MxK]*B[NxK]^T, bf16 in, fp32 accum --------
// 128x128 tile, BK=32, K=1024 fixed, A/B row stride 1024. LDS chunk (r,cpos) holds
// source chunk cpos^((r>>1)&3) -> frag ds_read_b128 is 2-way (free).
// MODE: 0 = bf16 out, 1 = f32 out, 2 = f16 out, 3 = bf16 out with fused RoPE.
template <int MODE>
__device__ __forceinline__ void gemm128_bt(const unsigned short* __restrict__ A,
                                           const unsigned short* __restrict__ B,
                                           void* __restrict__ Cv,
                                           int m0, int n0, int ldc,
                                           unsigned short* As, unsigned short* Bs) {
    const int tid = threadIdx.x;
    const int w = tid >> 6, lane = tid & 63;
    const int quad = lane >> 4, l15 = lane & 15;
    const int wm = w & 1, wn = w >> 1;

    f32x4 acc[4][4];
#pragma unroll
    for (int mt = 0; mt < 4; ++mt)
#pragma unroll
        for (int nt = 0; nt < 4; ++nt) acc[mt][nt] = f32x4{0.f, 0.f, 0.f, 0.f};

    for (int k0 = 0; k0 < 1024; k0 += 32) {
        __syncthreads();
#pragma unroll
        for (int i = 0; i < 2; ++i) {
            int L = (w * 2 + i) * 64 + lane;      // chunk index in tile
            int r = L >> 2;
            int c = (L & 3) ^ ((r >> 1) & 3);     // swizzled source chunk
            gl_lds16(A + (size_t)(m0 + r) * 1024 + k0 + c * 8, As + L * 8);
            gl_lds16(B + (size_t)(n0 + r) * 1024 + k0 + c * 8, Bs + L * 8);
        }
        __syncthreads();

        bf16x8 af[4], bfr[4];
#pragma unroll
        for (int mt = 0; mt < 4; ++mt) {
            int row = wm * 64 + mt * 16 + l15;
            af[mt] = *(const bf16x8*)(As + row * 32 + (quad ^ ((row >> 1) & 3)) * 8);
        }
#pragma unroll
        for (int nt = 0; nt < 4; ++nt) {
            int row = wn * 64 + nt * 16 + l15;
            bfr[nt] = *(const bf16x8*)(Bs + row * 32 + (quad ^ ((row >> 1) & 3)) * 8);
        }
#pragma unroll
        for (int mt = 0; mt < 4; ++mt)
#pragma unroll
            for (int nt = 0; nt < 4; ++nt)
                acc[mt][nt] = MFMA_BF16(af[mt], bfr[nt], acc[mt][nt]);
    }

    // ---- fused RoPE (MODE 3): ch = nt*16+l15 (row-independent), pp = ch>>1 ----
    float invf[4], sgn = 0.f;
    if constexpr (MODE == 3) {
        sgn = (l15 & 1) ? 1.0f : -1.0f;   // odd lane: +p*sin ; even lane: -p*sin
#pragma unroll
        for (int nt = 0; nt < 4; ++nt)
            invf[nt] = exp2f(-0.41524101186092029f * (float)((nt * 16 + l15) >> 1));
    }

#pragma unroll
    for (int mt = 0; mt < 4; ++mt) {
        int grow = m0 + wm * 64 + mt * 16 + quad * 4;
#pragma unroll
        for (int nt = 0; nt < 4; ++nt) {
            int gcol = n0 + wn * 64 + nt * 16 + l15;
#pragma unroll
            for (int r = 0; r < 4; ++r) {
                float val = acc[mt][nt][r];
                size_t idx = (size_t)(grow + r) * ldc + gcol;
                if constexpr (MODE == 0) {
                    ((unsigned short*)Cv)[idx] = f2bf(val);
                } else if constexpr (MODE == 1) {
                    ((float*)Cv)[idx] = val;
                } else if constexpr (MODE == 2) {
                    _Float16 hv = (_Float16)val;
                    ((unsigned short*)Cv)[idx] = __builtin_bit_cast(unsigned short, hv);
                } else {
                    float p = __shfl_xor(val, 1);              // pair partner channel
                    float pos = (float)((grow + r) & 2047);    // seq position
                    float ang = pos * invf[nt];
                    float out = val * __cosf(ang) + sgn * p * __sinf(ang);
                    ((unsigned short*)Cv)[idx] = f2bf(out);
                }
            }
        }
    }
}

// Q/K: bf16 + fused RoPE (ldc 1024). V: C = Wv * X^T = V^T[ch][token] f16 (ldc 4096).
__global__ __launch_bounds__(256) void gemm_qkv(const unsigned short* __restrict__ X,
                                                const unsigned short* __restrict__ Wq,
                                                const unsigned short* __restrict__ Wk,
                                                const unsigned short* __restrict__ Wv,
                                                unsigned short* __restrict__ Qo,
                                                unsigned short* __restrict__ Ko,
                                                unsigned short* __restrict__ Vt) {
    __shared__ unsigned short As[128 * 32];
    __shared__ unsigned short Bs[128 * 32];
    int y = blockIdx.y;
    if (y < 16) {
        int sel = y >> 3;
        int m0 = blockIdx.x * 128;         // tokens
        int n0 = (y & 7) * 128;            // channels
        const unsigned short* B = sel ? Wk : Wq;
        unsigned short* C = sel ? Ko : Qo;
        gemm128_bt<3>(X, B, C, m0, n0, 1024, As, Bs);
    } else {
        int m0 = (y & 7) * 128;            // channels
        int n0 = blockIdx.x * 128;         // tokens
        gemm128_bt<2>(Wv, X, Vt, m0, n0, 4096, As, Bs);
    }
}

__global__ __launch_bounds__(256) void gemm_out(const unsigned short* __restrict__ A,
                                                const unsigned short* __restrict__ Wo,
                                                float* __restrict__ C) {
    __shared__ unsigned short As[128 * 32];
    __shared__ unsigned short Bs[128 * 32];
    gemm128_bt<1>(A, Wo, C, blockIdx.x * 128, blockIdx.y * 128, 1024, As, Bs);
}

// ---------------- Flash attention: 16x16 MFMA, 2-wave blocks, grid 2048 ------------
// Round-8 wave structure (16q/wave, single-buffer K/V, mask peeled to diagonal,
// rowsum via ones-MFMA) but block = 2 waves x 32 q-rows: LDS 20.6KB -> 7 blocks/CU
// resident (vs 4 in round 8). The kernel is latency-chain-bound; resident blocks/CU
// is the measured dominant variable (r8 4/CU=54us, r10 2/CU=67us).
#define FBODY(KB, MASKED)                                                               \
    {                                                                                   \
        const int kb_ = (KB);                                                           \
        f32x4 sc[4];                                                                    \
        _Pragma("unroll")                                                               \
        for (int nt = 0; nt < 4; ++nt) {                                                \
            int row = nt * 16 + l15;                                                    \
            int cof = (quad ^ (row & 7)) * 8;                                           \
            bf16x8 kf0 = *(const bf16x8*)(Ks + row * 64 + cof);                         \
            bf16x8 kf1 = *(const bf16x8*)(Ks + row * 64 + (cof ^ 32));                  \
            f32x4 z = f32x4{0.f, 0.f, 0.f, 0.f};                                        \
            sc[nt] = MFMA_BF16(qf0, kf0, z);                                            \
            sc[nt] = MFMA_BF16(qf1, kf1, sc[nt]);                                       \
        }                                                                               \
        unsigned short* Pw = Ps[w];                                                     \
        _Pragma("unroll")                                                               \
        for (int nt = 0; nt < 4; ++nt) {                                                \
            float e[4];                                                                 \
            _Pragma("unroll")                                                           \
            for (int r = 0; r < 4; ++r) {                                               \
                float ev = exp2f(sc[nt][r]);                                            \
                if (MASKED) {                                                           \
                    int kpos = kb_ * 64 + nt * 16 + l15;                                \
                    int qpos = qpos0 + quad * 4 + r;                                    \
                    ev = (kpos > qpos) ? 0.f : ev;                                      \
                }                                                                       \
                e[r] = ev;                                                              \
            }                                                                           \
            unsigned pk01 = __builtin_bit_cast(unsigned,                                \
                                __builtin_amdgcn_cvt_pkrtz(e[0], e[1]));                \
            unsigned pk23 = __builtin_bit_cast(unsigned,                                \
                                __builtin_amdgcn_cvt_pkrtz(e[2], e[3]));                \
            int col = nt * 16 + l15;                                                    \
            Pw[(quad * 4 + 0) * 72 + col] = (unsigned short)pk01;                       \
            Pw[(quad * 4 + 1) * 72 + col] = (unsigned short)(pk01 >> 16);               \
            Pw[(quad * 4 + 2) * 72 + col] = (unsigned short)pk23;                       \
            Pw[(quad * 4 + 3) * 72 + col] = (unsigned short)(pk23 >> 16);               \
        }                                                                               \
        __asm__ volatile("s_waitcnt lgkmcnt(0)" ::: "memory");                          \
        f16x8 pf0 = *(const f16x8*)(Pw + l15 * 72 + quad * 8);                          \
        f16x8 pf1 = *(const f16x8*)(Pw + l15 * 72 + 32 + quad * 8);                     \
        lacc = MFMA_F16(pf0, ones, lacc);                                               \
        lacc = MFMA_F16(pf1, ones, lacc);                                               \
        _Pragma("unroll")                                                               \
        for (int nt = 0; nt < 4; ++nt) {                                                \
            int row = nt * 16 + l15;                                                    \
            int cof = (quad ^ (row & 7)) * 8;                                           \
            f16x8 vf0 = *(const f16x8*)(Vs + row * 64 + cof);                           \
            f16x8 vf1 = *(const f16x8*)(Vs + row * 64 + (cof ^ 32));                    \
            accO[nt] = MFMA_F16(pf0, vf0, accO[nt]);                                    \
            accO[nt] = MFMA_F16(pf1, vf1, accO[nt]);                                    \
        }                                                                               \
    }

__global__ __launch_bounds__(128) void flash_attn(const unsigned short* __restrict__ Q,
                                                  const unsigned short* __restrict__ Kb,
                                                  const unsigned short* __restrict__ Vt,
                                                  unsigned short* __restrict__ O) {
    int id = blockIdx.x;               // grid 2048: 64 q-tiles of 32 rows x 32 bh
    int xcd = id & 7;
    int sl = id >> 3;                  // [0,256)
    int rr = sl >> 6;                  // 0..3
    int j  = sl & 63;
    int qt = (rr & 1) ? (63 - j) : j;  // balanced pairing across rounds
    int bh = xcd + 8 * rr;             // 4 bh per XCD -> K/V streams L2-resident
    int b = bh >> 4, h = bh & 15;
    int tid = threadIdx.x, w = tid >> 6, lane = tid & 63;
    int quad = lane >> 4, l15 = lane & 15;
    int qrow0 = b * 2048 + qt * 32 + w * 16;
    int qpos0 = qt * 32 + w * 16;
    int nkb = (qt >> 1) + 1;           // key blocks needed (64-wide)

    __shared__ unsigned short Ks[64 * 64];     // bf16 [key][d], chunk-swizzled
    __shared__ unsigned short Vs[64 * 64];     // f16  [d][key], chunk-swizzled
    __shared__ unsigned short Ps[2][16 * 72];  // f16 per-wave P scratch, stride 72

    bf16x8 qf0, qf1;
    {
        const unsigned short* qp = Q + (size_t)(qrow0 + l15) * 1024 + h * 64 + quad * 8;
        qf0 = *(const bf16x8*)qp;
        qf1 = *(const bf16x8*)(qp + 32);
    }
    f16x8 ones;
#pragma unroll
    for (int jj = 0; jj < 8; ++jj) ones[jj] = (_Float16)1.0f;

    // staging: 512 chunks/tile over 128 lanes x 4 iters. chunk L: row r=L>>3,
    // lds col cpos=L&7 holds source chunk cpos^(r&7).
    const unsigned short* KgA[4];
    const unsigned short* VgA[4];
    int Ldst[4];
#pragma unroll
    for (int i = 0; i < 4; ++i) {
        int L = i * 128 + tid;
        int r = L >> 3, cpos = L & 7;
        int c = cpos ^ (r & 7);
        Ldst[i] = L * 8;
        KgA[i] = Kb + (size_t)(b * 2048 + r) * 1024 + h * 64 + c * 8;
        VgA[i] = Vt + (size_t)(h * 64 + r) * 4096 + b * 2048 + c * 8;
    }

    f32x4 accO[4];
#pragma unroll
    for (int nt = 0; nt < 4; ++nt) accO[nt] = f32x4{0.f, 0.f, 0.f, 0.f};
    f32x4 lacc = f32x4{0.f, 0.f, 0.f, 0.f};

    for (int kb = 0; kb < nkb; ++kb) {
        __syncthreads();                     // previous compute done before restage
        {
            size_t ko = (size_t)kb * 64 * 1024;
            size_t vo = (size_t)kb * 64;
#pragma unroll
            for (int i = 0; i < 4; ++i) {
                gl_lds16(KgA[i] + ko, Ks + Ldst[i]);
                gl_lds16(VgA[i] + vo, Vs + Ldst[i]);
            }
        }
        __syncthreads();                     // vmcnt drain + visibility
        if (kb < nkb - 1) {
            FBODY(kb, 0)
        } else {
            FBODY(kb, 1)                     // last key-block: diagonal mask
        }
    }

    // ---- epilogue: O / rowsum (lacc reg r = rowsum of q-row quad*4+r) ----
    float inv[4];
#pragma unroll
    for (int r = 0; r < 4; ++r) inv[r] = 1.0f / lacc[r];
#pragma unroll
    for (int nt = 0; nt < 4; ++nt)
#pragma unroll
        for (int r = 0; r < 4; ++r)
            O[(size_t)(qrow0 + quad * 4 + r) * 1024 + h * 64 + nt * 16 + l15] =
                f2bf(accO[nt][r] * inv[r]);
}

extern "C" void kernel_launch(void* const* d_in, const int* in_sizes, int n_in,
                              void* d_out, int out_size, void* d_ws, size_t ws_size,
                              hipStream_t stream) {
    (void)in_sizes; (void)n_in; (void)out_size; (void)ws_size;
    const float* x  = (const float*)d_in[0];
    const float* wq = (const float*)d_in[1];
    const float* wk = (const float*)d_in[2];
    const float* wv = (const float*)d_in[3];
    const float* wo = (const float*)d_in[4];
    float* out = (float*)d_out;

    const size_t T = (size_t)4096 * 1024;
    const size_t W = (size_t)1024 * 1024;
    unsigned short* Q   = (unsigned short*)d_ws;
    unsigned short* K   = Q + T;
    unsigned short* Vt  = K + T;      // f16 [ch][token], ldc 4096
    unsigned short* xb  = Vt + T;
    unsigned short* AO  = xb;         // alias: xb dead after gemm_qkv
    unsigned short* wqb = xb + T;
    unsigned short* wkb = wqb + W;
    unsigned short* wvb = wkb + W;
    unsigned short* wob = wvb + W;

    cvt_all  <<<dim3(4096),   256, 0, stream>>>(x, wq, wk, wv, wo, xb, wqb, wkb, wvb, wob);
    gemm_qkv <<<dim3(32, 24), 256, 0, stream>>>(xb, wqb, wkb, wvb, Q, K, Vt);
    flash_attn<<<dim3(2048),  128, 0, stream>>>(Q, K, Vt, AO);
    gemm_out <<<dim3(32, 8),  256, 0, stream>>>(AO, wob, out);
}